// Round 1
// baseline (457.505 us; speedup 1.0000x reference)
//
#include <hip/hip_runtime.h>

// Problem constants: B=32, T=2048, C=1152, O=29.
// out[b,o] = ( sum_c W[o,c] * (s[b,c]/64 - 2T) + T*bias[o] ) / length[b]
// where s[b,c] = sum_t x[b,t,c].

#define PB 32
#define PT 2048
#define PC 1152
#define PO 29
#define TSPLIT 32               // T-parallel slabs per batch
#define ROWS (PT / TSPLIT)      // 64 rows per slab
#define C4 (PC / 4)             // 288 float4 columns per row == block size of k1

// ---------------------------------------------------------------------------
// Kernel 1: partial temporal sums, no atomics, no memset.
// grid = (B, TSPLIT), block = 288 (== C4).  Thread tid owns float4 column tid.
// Streams 64 contiguous rows (288 KB contiguous region per block), writes one
// float4 partial per thread: sp[b][p][c4] = sum over slab rows.
// Every element of sp is written exactly once -> poison-safe, deterministic.
// ---------------------------------------------------------------------------
__global__ __launch_bounds__(288) void sum_slab_kernel(const float* __restrict__ x,
                                                       float* __restrict__ sp) {
    const int b   = blockIdx.x;
    const int p   = blockIdx.y;
    const int tid = threadIdx.x;          // 0..287 == c4 column index

    const float4* __restrict__ src =
        (const float4*)x + ((size_t)b * PT + (size_t)p * ROWS) * C4 + tid;

    float4 acc = make_float4(0.f, 0.f, 0.f, 0.f);

#pragma unroll 8
    for (int t = 0; t < ROWS; ++t) {
        float4 v = src[(size_t)t * C4];
        acc.x += v.x; acc.y += v.y; acc.z += v.z; acc.w += v.w;
    }

    float4* __restrict__ dst = (float4*)sp + ((size_t)b * TSPLIT + p) * C4 + tid;
    *dst = acc;
}

// ---------------------------------------------------------------------------
// Kernel 2: reduce partials over p, project with W, finish.
// grid = (B), block = 256.
//   phase 1: s_hat[c] = (sum_p sp[b][p][c]) * (1/64) - 2*T     (into LDS)
//   phase 2: wave w handles o = w, w+4, ... ; dot(W[o,:], s_hat) via
//            lane-strided loads + wave-64 shuffle reduction.
//   out[b,o] = (dot + T*bias[o]) / length[b]
// ---------------------------------------------------------------------------
__global__ __launch_bounds__(256) void finish_kernel(const float* __restrict__ sp,
                                                     const float* __restrict__ W,
                                                     const float* __restrict__ bias,
                                                     const int* __restrict__ length,
                                                     float* __restrict__ out) {
    const int b   = blockIdx.x;
    const int tid = threadIdx.x;

    __shared__ float s_hat[PC];

    const float4* __restrict__ spb = (const float4*)sp + (size_t)b * TSPLIT * C4;

    // Phase 1: p-reduction. Thread covers c4 = tid and (if tid<32) 256+tid.
    for (int c4 = tid; c4 < C4; c4 += 256) {
        float4 a = make_float4(0.f, 0.f, 0.f, 0.f);
#pragma unroll 8
        for (int p = 0; p < TSPLIT; ++p) {
            float4 v = spb[(size_t)p * C4 + c4];
            a.x += v.x; a.y += v.y; a.z += v.z; a.w += v.w;
        }
        const float scale = 1.0f / 64.0f;
        const float shift = -2.0f * (float)PT;
        s_hat[c4 * 4 + 0] = a.x * scale + shift;
        s_hat[c4 * 4 + 1] = a.y * scale + shift;
        s_hat[c4 * 4 + 2] = a.z * scale + shift;
        s_hat[c4 * 4 + 3] = a.w * scale + shift;
    }
    __syncthreads();

    // Phase 2: projection. 4 waves; wave w handles o = w, w+4, ...
    const int wave = tid >> 6;
    const int lane = tid & 63;
    const float inv_len = 1.0f / (float)length[b];

    for (int o = wave; o < PO; o += 4) {
        const float* __restrict__ Wo = W + (size_t)o * PC;
        float dot = 0.f;
#pragma unroll
        for (int c = lane; c < PC; c += 64) {
            dot += Wo[c] * s_hat[c];
        }
#pragma unroll
        for (int off = 32; off > 0; off >>= 1) {
            dot += __shfl_down(dot, off);
        }
        if (lane == 0) {
            out[b * PO + o] = (dot + (float)PT * bias[o]) * inv_len;
        }
    }
}

extern "C" void kernel_launch(void* const* d_in, const int* in_sizes, int n_in,
                              void* d_out, int out_size, void* d_ws, size_t ws_size,
                              hipStream_t stream) {
    const float* x      = (const float*)d_in[0];
    const int*   length = (const int*)d_in[1];
    const float* W      = (const float*)d_in[2];
    const float* bias   = (const float*)d_in[3];
    float*       out    = (float*)d_out;
    float*       sp     = (float*)d_ws;   // [B, TSPLIT, C] partial sums (4.7 MB)

    dim3 g1(PB, TSPLIT);
    sum_slab_kernel<<<g1, C4, 0, stream>>>(x, sp);

    finish_kernel<<<PB, 256, 0, stream>>>(sp, W, bias, length, out);
}

// Round 2
// 419.715 us; speedup vs baseline: 1.0900x; 1.0900x over previous
//
#include <hip/hip_runtime.h>

// Problem constants: B=32, T=2048, C=1152, O=29.
// out[b,o] = ( sum_c W[o,c] * (s[b,c]/64 - 2T) + T*bias[o] ) / length[b],
//            s[b,c] = sum_t x[b,t,c].
// Decomposition: per (b, slab) block computes d[b,s,o] = sum_c W[o,c]*(s_slab[c]/64 - 2*SROWS)
// so that out[b,o] = ( sum_s d[b,s,o] + T*bias[o] ) / length[b].

#define PB 32
#define PT 2048
#define PC 1152
#define PO 29
#define NS 16                // slabs per batch
#define SROWS (PT / NS)      // 128 rows per slab
#define C4 (PC / 4)          // 288 float4 per row
#define BT 576               // block threads = 9 full waves = exactly 2 rows of float4
#define PASSES (SROWS / 2)   // 64 two-row passes per block

// ---------------------------------------------------------------------------
// Kernel 1: stream a 128-row slab (590 KB contiguous), reduce over rows per
// channel, fold affine, project onto the 29 W rows in-block, emit 29 floats.
// grid = (B, NS), block = 576. No atomics, every zp element written once.
// ---------------------------------------------------------------------------
__global__ __launch_bounds__(BT) void slab_project_kernel(
    const float* __restrict__ x,
    const float* __restrict__ W,
    float* __restrict__ zp)            // [PB][NS][PO]
{
    const int b   = blockIdx.x;
    const int s   = blockIdx.y;
    const int tid = threadIdx.x;       // 0..575

    // Thread owns float4 column (tid % 288); consecutive tid = consecutive
    // addresses, 576 float4 = exactly 2 rows -> stride BT keeps column fixed.
    const float4* __restrict__ src =
        (const float4*)x + ((size_t)b * PT + (size_t)s * SROWS) * C4 + tid;

    float4 acc = make_float4(0.f, 0.f, 0.f, 0.f);
#pragma unroll 8
    for (int t = 0; t < PASSES; ++t) {
        float4 v = src[(size_t)t * BT];
        acc.x += v.x; acc.y += v.y; acc.z += v.z; acc.w += v.w;
    }

    // Stage both row-parity partials: lds[phase][c], phase = tid/288.
    __shared__ float lds[2 * PC];
    {
        const int phase = tid / C4;
        const int c4    = tid % C4;
        float4* l4 = (float4*)(lds + phase * PC) + c4;
        *l4 = acc;
    }
    __syncthreads();

    // Phase-reduce + affine fold, in place into lds[0..1151].
    // Each address in [0,1152) is read and written by exactly one thread.
    {
        const float scale = 1.0f / 64.0f;
        const float shift = -2.0f * (float)SROWS;   // -256 per slab
        const int c0 = tid;
        const int c1 = tid + BT;
        float v0 = (lds[c0] + lds[PC + c0]) * scale + shift;
        float v1 = (lds[c1] + lds[PC + c1]) * scale + shift;
        lds[c0] = v0;
        lds[c1] = v1;
    }
    __syncthreads();

    // Projection: 9 waves, wave w handles o = w, w+9, w+18, (w+27).
    const int wave = tid >> 6;
    const int lane = tid & 63;
    for (int o = wave; o < PO; o += 9) {
        const float* __restrict__ Wo = W + (size_t)o * PC;
        float dot = 0.f;
#pragma unroll
        for (int c = lane; c < PC; c += 64) {
            dot += Wo[c] * lds[c];
        }
#pragma unroll
        for (int off = 32; off > 0; off >>= 1) {
            dot += __shfl_down(dot, off);
        }
        if (lane == 0) {
            zp[((size_t)b * NS + s) * PO + o] = dot;
        }
    }
}

// ---------------------------------------------------------------------------
// Kernel 2: reduce the 16 slab partials per (b,o), epilogue. 59 KB total read.
// grid = (B), block = 64 (lanes 29..63 idle).
// ---------------------------------------------------------------------------
__global__ __launch_bounds__(64) void reduce_kernel(
    const float* __restrict__ zp,
    const float* __restrict__ bias,
    const int*  __restrict__ length,
    float* __restrict__ out)
{
    const int b = blockIdx.x;
    const int o = threadIdx.x;
    if (o < PO) {
        float acc = 0.f;
#pragma unroll
        for (int s = 0; s < NS; ++s) {
            acc += zp[((size_t)b * NS + s) * PO + o];
        }
        out[b * PO + o] = (acc + (float)PT * bias[o]) / (float)length[b];
    }
}

extern "C" void kernel_launch(void* const* d_in, const int* in_sizes, int n_in,
                              void* d_out, int out_size, void* d_ws, size_t ws_size,
                              hipStream_t stream) {
    const float* x      = (const float*)d_in[0];
    const int*   length = (const int*)d_in[1];
    const float* W      = (const float*)d_in[2];
    const float* bias   = (const float*)d_in[3];
    float*       out    = (float*)d_out;
    float*       zp     = (float*)d_ws;   // [B][NS][PO] = 59 KB

    dim3 g1(PB, NS);
    slab_project_kernel<<<g1, BT, 0, stream>>>(x, W, zp);

    reduce_kernel<<<PB, 64, 0, stream>>>(zp, bias, length, out);
}